// Round 2
// baseline (268.627 us; speedup 1.0000x reference)
//
#include <hip/hip_runtime.h>

// R6: fused kernel with wave-PAIR split gauss chain.
// - 1024-thread blocks, 8 samples, 64KB LDS (2 blocks/CU -> 32 waves/CU, full occ).
// - each sample's 8-stage chain is split across 2 waves (mt-split in stage_a,
//   nt-split in stage_b); per-stage {reads -> barrier -> mfma+writes -> barrier}
//   handles the in-place transpose hazard across the pair.
// - dense0: K split 16 ways (8 its/wave), partials reduced across 16 waves.

typedef _Float16 f16x8 __attribute__((ext_vector_type(8)));
typedef _Float16 f16x4 __attribute__((ext_vector_type(4)));
typedef float    f32x4 __attribute__((ext_vector_type(4)));

// ws layout (halves): [0] wm0 tiled [128][80][32]; K~ [4][64][64]; padded weights
#define KT_OFF    327680
#define W0P_OFF   344064               // [16][64], rows>=8 zero
#define W1P_OFF   345088               // [16][32], cols>=8 zero
#define W2P_OFF   345600               // [32][32], cols>=16 zero
#define W3P_OFF   346624               // [64][32]

__global__ void prep_all(const float* __restrict__ s0, const float* __restrict__ s1,
                         const float* __restrict__ s2, const float* __restrict__ s3,
                         const float* __restrict__ w0, const float* __restrict__ w1,
                         const float* __restrict__ w2, const float* __restrict__ w3,
                         const float* __restrict__ wm0, _Float16* __restrict__ base) {
  int bid = blockIdx.x, tid = threadIdx.x;
  if (bid < 1280) {
    // wm0 fp32 [80][4096] -> fp16 tiled [kc][n][32]
    int idx = bid * 256 + tid;
    int kc = idx / 2560, rem = idx % 2560;
    int n = rem >> 5, o = rem & 31;
    base[idx] = (_Float16)wm0[n * 4096 + kc * 32 + o];
  } else if (bid == 1280) {
    // K~ : L1-normalized gaussian rows, fp16 [4][64][64]
    int li = tid >> 6, i = tid & 63;
    float sg = (li == 0) ? s0[0] : (li == 1) ? s1[0] : (li == 2) ? s2[0] : s3[0];
    float denom = 2.0f * sg * sg;
    float sum = 0.0f;
    for (int j = 0; j < 64; ++j) {
      float d = (float)(i - j);
      sum += expf(-(d * d) / denom);
    }
    float inv = 1.0f / fmaxf(sum, 1e-12f);
    for (int j = 0; j < 64; ++j) {
      float d = (float)(i - j);
      base[KT_OFF + (li * 64 + i) * 64 + j] = (_Float16)(expf(-(d * d) / denom) * inv);
    }
  } else {
    // small layer weights, zero-padded to MFMA tiles
    for (int r = tid; r < 4608; r += 256) {
      float v;
      if (r < 1024)      { int o = r >> 6, c = r & 63;             v = (o < 8)  ? w0[o * 64 + c] : 0.0f; }
      else if (r < 1536) { int q = r - 1024; int o = q >> 5, c = q & 31; v = (c < 8)  ? w1[o * 8 + c]  : 0.0f; }
      else if (r < 2560) { int q = r - 1536; int o = q >> 5, c = q & 31; v = (c < 16) ? w2[o * 16 + c] : 0.0f; }
      else               { int q = r - 2560; int o = q >> 5, c = q & 31; v = w3[o * 32 + c]; }
      base[W0P_OFF + r] = (_Float16)v;
    }
  }
}

__device__ __forceinline__ float leaky(float v) { return v > 0.0f ? v : 0.01f * v; }

// swizzled offset (halves) in an 8KB 64x64 fp16 buffer: 16B chunk j -> j ^ (row&7) ^ sx
// sx = per-sample XOR so that dense A-reads (lane -> sample) spread across chunks.
__device__ __forceinline__ int swz(int sx, int row, int c) {
  return row * 64 + ((((c >> 3) ^ (row & 7) ^ sx) & 7) << 3) + (c & 7);
}

// stage A, pair-split on mt: xpT[o][h] over P from act_R[h][c] and w[o][c].
// this wave handles mt = {2*half, 2*half+1}; computes all NT nt col-tiles.
template<int NT, int KC, int KPAD>
__device__ __forceinline__ void stage_a2(_Float16* __restrict__ P, int sx, int half,
                                         const _Float16* __restrict__ wp, const float* bv,
                                         int lo, int hi) {
  f16x8 a[2][KC];
#pragma unroll
  for (int m = 0; m < 2; ++m)
#pragma unroll
    for (int kc = 0; kc < KC; ++kc)
      a[m][kc] = *(const f16x8*)(P + swz(sx, (half * 2 + m) * 16 + lo, kc * 32 + hi * 8));
  f16x8 wf[NT][KC];
#pragma unroll
  for (int nt = 0; nt < NT; ++nt)
#pragma unroll
    for (int kc = 0; kc < KC; ++kc)
      wf[nt][kc] = *(const f16x8*)(wp + (nt * 16 + lo) * KPAD + kc * 32 + hi * 8);
  __syncthreads();     // all pair reads of act done before anyone writes xpT
#pragma unroll
  for (int m = 0; m < 2; ++m)
#pragma unroll
    for (int nt = 0; nt < NT; ++nt) {
      f32x4 acc = {0.0f, 0.0f, 0.0f, 0.0f};
#pragma unroll
      for (int kc = 0; kc < KC; ++kc)
        acc = __builtin_amdgcn_mfma_f32_16x16x32_f16(a[m][kc], wf[nt][kc], acc, 0, 0, 0);
      f16x4 hv;
#pragma unroll
      for (int r = 0; r < 4; ++r) hv[r] = (_Float16)(acc[r] + bv[nt]);
      *(f16x4*)(P + swz(sx, nt * 16 + lo, (half * 2 + m) * 16 + hi * 4)) = hv;
    }
  __syncthreads();     // xpT visible before next stage reads
}

// stage B, pair-split on nt: act_R[i][o] = leaky(sum_j K~[i][j] * xpT[o][j]).
// this wave handles nt = {2*half, 2*half+1}; reads all MT ot-tiles of xpT.
template<int MT>
__device__ __forceinline__ void stage_b2(_Float16* __restrict__ P, int sx, int half,
                                         const _Float16* __restrict__ kmat, int lo, int hi) {
  f16x8 ax[MT][2];
#pragma unroll
  for (int ot = 0; ot < MT; ++ot)
#pragma unroll
    for (int kc = 0; kc < 2; ++kc)
      ax[ot][kc] = *(const f16x8*)(P + swz(sx, ot * 16 + lo, kc * 32 + hi * 8));
  f16x8 kb[2][2];
#pragma unroll
  for (int n = 0; n < 2; ++n)
#pragma unroll
    for (int kc = 0; kc < 2; ++kc)
      kb[n][kc] = *(const f16x8*)(kmat + ((half * 2 + n) * 16 + lo) * 64 + kc * 32 + hi * 8);
  __syncthreads();     // all pair reads of xpT done before anyone writes act
#pragma unroll
  for (int ot = 0; ot < MT; ++ot)
#pragma unroll
    for (int n = 0; n < 2; ++n) {
      f32x4 acc = {0.0f, 0.0f, 0.0f, 0.0f};
#pragma unroll
      for (int kc = 0; kc < 2; ++kc)
        acc = __builtin_amdgcn_mfma_f32_16x16x32_f16(ax[ot][kc], kb[n][kc], acc, 0, 0, 0);
      f16x4 hv;
#pragma unroll
      for (int r = 0; r < 4; ++r) hv[r] = (_Float16)leaky(acc[r]);
      *(f16x4*)(P + swz(sx, (half * 2 + n) * 16 + lo, ot * 16 + hi * 4)) = hv;
    }
  __syncthreads();     // act visible before next stage reads
}

__global__ __launch_bounds__(1024, 6)
void fused(const float* __restrict__ x,
           const float* __restrict__ bb0, const float* __restrict__ bb1,
           const float* __restrict__ bb2, const float* __restrict__ bb3,
           const _Float16* __restrict__ wsh,
           const float* __restrict__ bm0, const float* __restrict__ wm1,
           const float* __restrict__ bm1, float* __restrict__ out, int B) {
  __shared__ _Float16 lds[8][4096];   // 64KB: 8 samples x (64x64 fp16)
  const int tid = threadIdx.x;
  const int wv = tid >> 6, lane = tid & 63;
  const int lo = lane & 15, hi = lane >> 4;
  const int sample = wv >> 1, half = wv & 1;
  const int smp0 = blockIdx.x * 8;
  int smp = smp0 + sample;
  if (smp >= B) smp = B - 1;          // clamp; OOB outputs masked at final store
  _Float16* P = lds[sample];
  const int sx = sample;              // per-sample chunk XOR

  float bv0 = (lo < 8) ? bb0[lo] : 0.0f;
  float bv1 = bb1[lo];
  float bv2[2] = {bb2[lo], bb2[16 + lo]};
  float bv3[4] = {bb3[lo], bb3[16 + lo], bb3[32 + lo], bb3[48 + lo]};

  // ---- phase G: x -> act_R fp16 swizzled (pair-split on t), then 8 stages ----
  const float4* xv = (const float4*)(x + (size_t)smp * 4096);
#pragma unroll
  for (int tt = 0; tt < 8; ++tt) {
    int t = half * 8 + tt;
    float4 v = xv[t * 64 + lane];
    f16x4 hv;
    hv[0] = (_Float16)v.x; hv[1] = (_Float16)v.y; hv[2] = (_Float16)v.z; hv[3] = (_Float16)v.w;
    *(f16x4*)(P + swz(sx, t * 4 + hi, lo * 4)) = hv;
  }
  __syncthreads();                    // x staged before stage reads

  const _Float16* kt = wsh + KT_OFF;
  stage_a2<1, 2, 64>(P, sx, half, wsh + W0P_OFF, &bv0, lo, hi);
  stage_b2<1>(P, sx, half, kt + 0 * 4096, lo, hi);
  stage_a2<1, 1, 32>(P, sx, half, wsh + W1P_OFF, &bv1, lo, hi);
  stage_b2<1>(P, sx, half, kt + 1 * 4096, lo, hi);
  stage_a2<2, 1, 32>(P, sx, half, wsh + W2P_OFF, bv2, lo, hi);
  stage_b2<2>(P, sx, half, kt + 2 * 4096, lo, hi);
  stage_a2<4, 1, 32>(P, sx, half, wsh + W3P_OFF, bv3, lo, hi);
  stage_b2<4>(P, sx, half, kt + 3 * 4096, lo, hi);

  // ---- phase D0: out80 = wm0 @ h.  A rows = samples (8 valid of 16), 16-way K split ----
  f32x4 acc[5];
#pragma unroll
  for (int nt = 0; nt < 5; ++nt) { f32x4 z = {0.0f, 0.0f, 0.0f, 0.0f}; acc[nt] = z; }

  const _Float16* ap = &lds[lo & 7][0];
#pragma unroll 2
  for (int it = 0; it < 8; ++it) {
    int kc = wv * 8 + it;                  // 128 kc chunks of 32 halves
    int row = kc >> 1, cc = (kc & 1) * 32 + hi * 8;
    f16x8 a = *(const f16x8*)(ap + swz(lo & 7, row, cc));
    const _Float16* bp = wsh + (size_t)kc * 2560 + lo * 32 + hi * 8;
#pragma unroll
    for (int nt = 0; nt < 5; ++nt) {
      f16x8 b = *(const f16x8*)(bp + nt * 512);
      acc[nt] = __builtin_amdgcn_mfma_f32_16x16x32_f16(a, b, acc[nt], 0, 0, 0);
    }
  }
  __syncthreads();                         // all dense reads of lds done

  // partials into reused LDS: part[wv][m<8][80]  (16 waves x 640 floats = 40KB)
  float* scr = (float*)&lds[0][0];
  if (hi < 2) {
#pragma unroll
    for (int nt = 0; nt < 5; ++nt)
#pragma unroll
      for (int r = 0; r < 4; ++r)
        scr[wv * 640 + (hi * 4 + r) * 80 + nt * 16 + lo] = acc[nt][r];
  }
  __syncthreads();

  // reduce across 16 waves + bias + leaky -> h1[8][80]
  float* h1 = scr + 10240;
  for (int e = tid; e < 640; e += 1024) {
    int m = e / 80, n = e - m * 80;
    float v = bm0[n];
#pragma unroll
    for (int w = 0; w < 16; ++w) v += scr[w * 640 + e];
    h1[e] = leaky(v);
  }
  __syncthreads();

  // ---- phase D1: out60 = wm1 @ h1 ----
  if (tid < 480) {
    int m = tid / 60, n = tid - m * 60;
    float v = bm1[n];
    const float4* hr = (const float4*)(h1 + m * 80);
    const float4* wr = (const float4*)(wm1 + n * 80);
#pragma unroll
    for (int k2 = 0; k2 < 20; ++k2) {
      float4 hv = hr[k2], wv4 = wr[k2];
      v += hv.x * wv4.x + hv.y * wv4.y + hv.z * wv4.z + hv.w * wv4.w;
    }
    int s = smp0 + m;
    if (s < B) out[(size_t)s * 60 + n] = leaky(v);
  }
}

extern "C" void kernel_launch(void* const* d_in, const int* in_sizes, int n_in,
                              void* d_out, int out_size, void* d_ws, size_t ws_size,
                              hipStream_t stream) {
  const float* x   = (const float*)d_in[0];
  const float* w0  = (const float*)d_in[1];
  const float* b0  = (const float*)d_in[2];
  const float* s0  = (const float*)d_in[3];
  const float* w1  = (const float*)d_in[4];
  const float* b1  = (const float*)d_in[5];
  const float* s1  = (const float*)d_in[6];
  const float* w2  = (const float*)d_in[7];
  const float* b2  = (const float*)d_in[8];
  const float* s2  = (const float*)d_in[9];
  const float* w3  = (const float*)d_in[10];
  const float* b3  = (const float*)d_in[11];
  const float* s3  = (const float*)d_in[12];
  const float* wm0 = (const float*)d_in[13];
  const float* bm0 = (const float*)d_in[14];
  const float* wm1 = (const float*)d_in[15];
  const float* bm1 = (const float*)d_in[16];
  float* out = (float*)d_out;
  _Float16* wsh = (_Float16*)d_ws;

  int B = in_sizes[0] / 4096;

  prep_all<<<1282, 256, 0, stream>>>(s0, s1, s2, s3, w0, w1, w2, w3, wm0, wsh);
  fused<<<(B + 7) / 8, 1024, 0, stream>>>(x, b0, b1, b2, b3, wsh, bm0, wm1, bm1, out, B);
}

// Round 4
// 166.718 us; speedup vs baseline: 1.6113x; 1.6113x over previous
//
#include <hip/hip_runtime.h>

// R8: R7 structure (dual-sample wave-private gauss chains, 16-sample dense,
// 128KB LDS) with compile-time ordering pins fixing the post-timing divergence:
// - no __restrict__ on LDS stage pointers (alias-scope reordering hazard),
// - sched_barrier(0) pinning {stage entry} and {reads | mfma+writes} so the
//   in-place transpose's ds_reads can never be interleaved with its ds_writes.

typedef _Float16 f16x8 __attribute__((ext_vector_type(8)));
typedef _Float16 f16x4 __attribute__((ext_vector_type(4)));
typedef float    f32x4 __attribute__((ext_vector_type(4)));

// ws layout (halves): [0] wm0 tiled [128][80][32]; K~ [4][64][64]; padded weights
#define KT_OFF    327680
#define W0P_OFF   344064               // [16][64], rows>=8 zero
#define W1P_OFF   345088               // [16][32], cols>=8 zero
#define W2P_OFF   345600               // [32][32], cols>=16 zero
#define W3P_OFF   346624               // [64][32]

__global__ void prep_all(const float* __restrict__ s0, const float* __restrict__ s1,
                         const float* __restrict__ s2, const float* __restrict__ s3,
                         const float* __restrict__ w0, const float* __restrict__ w1,
                         const float* __restrict__ w2, const float* __restrict__ w3,
                         const float* __restrict__ wm0, _Float16* __restrict__ base) {
  int bid = blockIdx.x, tid = threadIdx.x;
  if (bid < 1280) {
    // wm0 fp32 [80][4096] -> fp16 tiled [kc][n][32]
    int idx = bid * 256 + tid;
    int kc = idx / 2560, rem = idx % 2560;
    int n = rem >> 5, o = rem & 31;
    base[idx] = (_Float16)wm0[n * 4096 + kc * 32 + o];
  } else if (bid == 1280) {
    // K~ : L1-normalized gaussian rows, fp16 [4][64][64]
    int li = tid >> 6, i = tid & 63;
    float sg = (li == 0) ? s0[0] : (li == 1) ? s1[0] : (li == 2) ? s2[0] : s3[0];
    float denom = 2.0f * sg * sg;
    float sum = 0.0f;
    for (int j = 0; j < 64; ++j) {
      float d = (float)(i - j);
      sum += expf(-(d * d) / denom);
    }
    float inv = 1.0f / fmaxf(sum, 1e-12f);
    for (int j = 0; j < 64; ++j) {
      float d = (float)(i - j);
      base[KT_OFF + (li * 64 + i) * 64 + j] = (_Float16)(expf(-(d * d) / denom) * inv);
    }
  } else {
    // small layer weights, zero-padded to MFMA tiles
    for (int r = tid; r < 4608; r += 256) {
      float v;
      if (r < 1024)      { int o = r >> 6, c = r & 63;             v = (o < 8)  ? w0[o * 64 + c] : 0.0f; }
      else if (r < 1536) { int q = r - 1024; int o = q >> 5, c = q & 31; v = (c < 8)  ? w1[o * 8 + c]  : 0.0f; }
      else if (r < 2560) { int q = r - 1536; int o = q >> 5, c = q & 31; v = (c < 16) ? w2[o * 16 + c] : 0.0f; }
      else               { int q = r - 2560; int o = q >> 5, c = q & 31; v = w3[o * 32 + c]; }
      base[W0P_OFF + r] = (_Float16)v;
    }
  }
}

__device__ __forceinline__ float leaky(float v) { return v > 0.0f ? v : 0.01f * v; }

// swizzled offset (halves) in an 8KB 64x64 fp16 buffer: 16B chunk j -> j ^ (row&7) ^ sx
__device__ __forceinline__ int swz(int sx, int row, int c) {
  return row * 64 + ((((c >> 3) ^ (row & 7) ^ sx) & 7) << 3) + (c & 7);
}

// stage A, dual-sample: xpT[o][h] from act_R[h][c] and w[o][c], for two buffers.
// weight fragments loaded once, reused for both samples.
template<int NT, int KC, int KPAD>
__device__ __forceinline__ void stage_a_dual(_Float16* PA, _Float16* PB,
                                             int sxA, int sxB,
                                             const _Float16* wp, const float* bv,
                                             int lo, int hi) {
  __builtin_amdgcn_sched_barrier(0);   // prior stage's writes stay above
  f16x8 aA[4][KC], aB[4][KC];
#pragma unroll
  for (int mt = 0; mt < 4; ++mt)
#pragma unroll
    for (int kc = 0; kc < KC; ++kc) {
      aA[mt][kc] = *(const f16x8*)(PA + swz(sxA, mt * 16 + lo, kc * 32 + hi * 8));
      aB[mt][kc] = *(const f16x8*)(PB + swz(sxB, mt * 16 + lo, kc * 32 + hi * 8));
    }
  f16x8 wf[NT][KC];
#pragma unroll
  for (int nt = 0; nt < NT; ++nt)
#pragma unroll
    for (int kc = 0; kc < KC; ++kc)
      wf[nt][kc] = *(const f16x8*)(wp + (nt * 16 + lo) * KPAD + kc * 32 + hi * 8);
  __builtin_amdgcn_sched_barrier(0);   // all reads above; all writes below
#pragma unroll
  for (int mt = 0; mt < 4; ++mt)
#pragma unroll
    for (int nt = 0; nt < NT; ++nt) {
      f32x4 accA = {0.0f, 0.0f, 0.0f, 0.0f};
      f32x4 accB = {0.0f, 0.0f, 0.0f, 0.0f};
#pragma unroll
      for (int kc = 0; kc < KC; ++kc) {
        accA = __builtin_amdgcn_mfma_f32_16x16x32_f16(aA[mt][kc], wf[nt][kc], accA, 0, 0, 0);
        accB = __builtin_amdgcn_mfma_f32_16x16x32_f16(aB[mt][kc], wf[nt][kc], accB, 0, 0, 0);
      }
      f16x4 hA, hB;
#pragma unroll
      for (int r = 0; r < 4; ++r) {
        hA[r] = (_Float16)(accA[r] + bv[nt]);
        hB[r] = (_Float16)(accB[r] + bv[nt]);
      }
      *(f16x4*)(PA + swz(sxA, nt * 16 + lo, mt * 16 + hi * 4)) = hA;
      *(f16x4*)(PB + swz(sxB, nt * 16 + lo, mt * 16 + hi * 4)) = hB;
    }
}

// stage B, dual-sample: act_R[i][o] = leaky(sum_j K~[i][j] * xpT[o][j])
template<int MT>
__device__ __forceinline__ void stage_b_dual(_Float16* PA, _Float16* PB,
                                             int sxA, int sxB,
                                             const _Float16* kmat, int lo, int hi) {
  __builtin_amdgcn_sched_barrier(0);   // prior stage's writes stay above
  f16x8 axA[MT][2], axB[MT][2];
#pragma unroll
  for (int ot = 0; ot < MT; ++ot)
#pragma unroll
    for (int kc = 0; kc < 2; ++kc) {
      axA[ot][kc] = *(const f16x8*)(PA + swz(sxA, ot * 16 + lo, kc * 32 + hi * 8));
      axB[ot][kc] = *(const f16x8*)(PB + swz(sxB, ot * 16 + lo, kc * 32 + hi * 8));
    }
  f16x8 kb[4][2];
#pragma unroll
  for (int nt = 0; nt < 4; ++nt)
#pragma unroll
    for (int kc = 0; kc < 2; ++kc)
      kb[nt][kc] = *(const f16x8*)(kmat + (nt * 16 + lo) * 64 + kc * 32 + hi * 8);
  __builtin_amdgcn_sched_barrier(0);   // all reads above; all writes below
#pragma unroll
  for (int ot = 0; ot < MT; ++ot)
#pragma unroll
    for (int nt = 0; nt < 4; ++nt) {
      f32x4 accA = {0.0f, 0.0f, 0.0f, 0.0f};
      f32x4 accB = {0.0f, 0.0f, 0.0f, 0.0f};
#pragma unroll
      for (int kc = 0; kc < 2; ++kc) {
        accA = __builtin_amdgcn_mfma_f32_16x16x32_f16(axA[ot][kc], kb[nt][kc], accA, 0, 0, 0);
        accB = __builtin_amdgcn_mfma_f32_16x16x32_f16(axB[ot][kc], kb[nt][kc], accB, 0, 0, 0);
      }
      f16x4 hA, hB;
#pragma unroll
      for (int r = 0; r < 4; ++r) {
        hA[r] = (_Float16)leaky(accA[r]);
        hB[r] = (_Float16)leaky(accB[r]);
      }
      *(f16x4*)(PA + swz(sxA, nt * 16 + lo, ot * 16 + hi * 4)) = hA;
      *(f16x4*)(PB + swz(sxB, nt * 16 + lo, ot * 16 + hi * 4)) = hB;
    }
}

__global__ __launch_bounds__(512, 2)
void fused(const float* __restrict__ x,
           const float* __restrict__ bb0, const float* __restrict__ bb1,
           const float* __restrict__ bb2, const float* __restrict__ bb3,
           const _Float16* __restrict__ wsh,
           const float* __restrict__ bm0, const float* __restrict__ wm1,
           const float* __restrict__ bm1, float* __restrict__ out, int B) {
  __shared__ _Float16 lds[16][4096];  // 128KB: 16 samples x (64x64 fp16)
  const int tid = threadIdx.x;
  const int wv = tid >> 6, lane = tid & 63;
  const int lo = lane & 15, hi = lane >> 4;
  const int smp0 = blockIdx.x * 16;
  int smpA = smp0 + wv;      if (smpA >= B) smpA = B - 1;
  int smpB = smp0 + wv + 8;  if (smpB >= B) smpB = B - 1;
  _Float16* PA = lds[wv];
  _Float16* PB = lds[wv + 8];
  const int sxA = wv, sxB = wv + 8;   // swz masks &7 internally

  float bv0 = (lo < 8) ? bb0[lo] : 0.0f;
  float bv1 = bb1[lo];
  float bv2[2] = {bb2[lo], bb2[16 + lo]};
  float bv3[4] = {bb3[lo], bb3[16 + lo], bb3[32 + lo], bb3[48 + lo]};

  // ---- phase G: x -> act_R fp16 swizzled, both samples, then 8 dual stages ----
  const float4* xvA = (const float4*)(x + (size_t)smpA * 4096);
  const float4* xvB = (const float4*)(x + (size_t)smpB * 4096);
#pragma unroll
  for (int t = 0; t < 16; ++t) {
    float4 vA = xvA[t * 64 + lane];
    float4 vB = xvB[t * 64 + lane];
    f16x4 hA, hB;
    hA[0] = (_Float16)vA.x; hA[1] = (_Float16)vA.y; hA[2] = (_Float16)vA.z; hA[3] = (_Float16)vA.w;
    hB[0] = (_Float16)vB.x; hB[1] = (_Float16)vB.y; hB[2] = (_Float16)vB.z; hB[3] = (_Float16)vB.w;
    *(f16x4*)(PA + swz(sxA, t * 4 + hi, lo * 4)) = hA;
    *(f16x4*)(PB + swz(sxB, t * 4 + hi, lo * 4)) = hB;
  }

  const _Float16* kt = wsh + KT_OFF;
  stage_a_dual<1, 2, 64>(PA, PB, sxA, sxB, wsh + W0P_OFF, &bv0, lo, hi);
  stage_b_dual<1>(PA, PB, sxA, sxB, kt + 0 * 4096, lo, hi);
  stage_a_dual<1, 1, 32>(PA, PB, sxA, sxB, wsh + W1P_OFF, &bv1, lo, hi);
  stage_b_dual<1>(PA, PB, sxA, sxB, kt + 1 * 4096, lo, hi);
  stage_a_dual<2, 1, 32>(PA, PB, sxA, sxB, wsh + W2P_OFF, bv2, lo, hi);
  stage_b_dual<2>(PA, PB, sxA, sxB, kt + 2 * 4096, lo, hi);
  stage_a_dual<4, 1, 32>(PA, PB, sxA, sxB, wsh + W3P_OFF, bv3, lo, hi);
  stage_b_dual<4>(PA, PB, sxA, sxB, kt + 3 * 4096, lo, hi);

  __syncthreads();   // all 16 sample buffers complete before cross-wave dense reads

  // ---- phase D0: out80 = wm0 @ h.  A rows = 16 samples (all valid), 8-way K split ----
  f32x4 acc[5];
#pragma unroll
  for (int nt = 0; nt < 5; ++nt) { f32x4 z = {0.0f, 0.0f, 0.0f, 0.0f}; acc[nt] = z; }

  const _Float16* ap = &lds[lo][0];
#pragma unroll 2
  for (int it = 0; it < 16; ++it) {
    int kc = wv * 16 + it;                 // 128 kc chunks of 32 halves
    int row = kc >> 1, cc = (kc & 1) * 32 + hi * 8;
    f16x8 a = *(const f16x8*)(ap + swz(lo, row, cc));
    const _Float16* bp = wsh + (size_t)kc * 2560 + lo * 32 + hi * 8;
#pragma unroll
    for (int nt = 0; nt < 5; ++nt) {
      f16x8 b = *(const f16x8*)(bp + nt * 512);
      acc[nt] = __builtin_amdgcn_mfma_f32_16x16x32_f16(a, b, acc[nt], 0, 0, 0);
    }
  }
  __syncthreads();                         // all dense reads of lds done

  // partials into reused LDS: part[wv][m<16][80]  (8 waves x 1280 floats = 40KB)
  float* scr = (float*)&lds[0][0];
#pragma unroll
  for (int nt = 0; nt < 5; ++nt)
#pragma unroll
    for (int r = 0; r < 4; ++r)
      scr[wv * 1280 + (hi * 4 + r) * 80 + nt * 16 + lo] = acc[nt][r];
  __syncthreads();

  // reduce across 8 waves + bias + leaky -> h1[16][80]
  float* h1 = scr + 10240;
  for (int e = tid; e < 1280; e += 512) {
    int m = e / 80, n = e - m * 80;
    float v = bm0[n];
#pragma unroll
    for (int w = 0; w < 8; ++w) v += scr[w * 1280 + e];
    h1[e] = leaky(v);
  }
  __syncthreads();

  // ---- phase D1: out60 = wm1 @ h1 ----
  for (int e = tid; e < 960; e += 512) {
    int m = e / 60, n = e - m * 60;
    float v = bm1[n];
    const float4* hr = (const float4*)(h1 + m * 80);
    const float4* wr = (const float4*)(wm1 + n * 80);
#pragma unroll
    for (int k2 = 0; k2 < 20; ++k2) {
      float4 hv = hr[k2], wv4 = wr[k2];
      v += hv.x * wv4.x + hv.y * wv4.y + hv.z * wv4.z + hv.w * wv4.w;
    }
    int s = smp0 + m;
    if (s < B) out[(size_t)s * 60 + n] = leaky(v);
  }
}

extern "C" void kernel_launch(void* const* d_in, const int* in_sizes, int n_in,
                              void* d_out, int out_size, void* d_ws, size_t ws_size,
                              hipStream_t stream) {
  const float* x   = (const float*)d_in[0];
  const float* w0  = (const float*)d_in[1];
  const float* b0  = (const float*)d_in[2];
  const float* s0  = (const float*)d_in[3];
  const float* w1  = (const float*)d_in[4];
  const float* b1  = (const float*)d_in[5];
  const float* s1  = (const float*)d_in[6];
  const float* w2  = (const float*)d_in[7];
  const float* b2  = (const float*)d_in[8];
  const float* s2  = (const float*)d_in[9];
  const float* w3  = (const float*)d_in[10];
  const float* b3  = (const float*)d_in[11];
  const float* s3  = (const float*)d_in[12];
  const float* wm0 = (const float*)d_in[13];
  const float* bm0 = (const float*)d_in[14];
  const float* wm1 = (const float*)d_in[15];
  const float* bm1 = (const float*)d_in[16];
  float* out = (float*)d_out;
  _Float16* wsh = (_Float16*)d_ws;

  int B = in_sizes[0] / 4096;

  prep_all<<<1282, 256, 0, stream>>>(s0, s1, s2, s3, w0, w1, w2, w3, wm0, wsh);
  fused<<<(B + 15) / 16, 512, 0, stream>>>(x, b0, b1, b2, b3, wsh, bm0, wm1, bm1, out, B);
}